// Round 3
// baseline (109.541 us; speedup 1.0000x reference)
//
#include <hip/hip_runtime.h>

// 3D spatial transformer (trilinear grid sample, zeros padding).
// src:  (1,1,160,192,224) f32
// flow: (1,3,160,192,224) f32   channel 0->d, 1->h, 2->w displacement
// out:  (1,1,160,192,224) f32
//
// R2: same as R1 but with native clang vector type for the nontemporal
// builtins (HIP_vector_type is a struct and is rejected).

constexpr int Dd = 160;
constexpr int Hh = 192;
constexpr int Ww = 224;
constexpr int HW = Hh * Ww;          // 43008
constexpr int N  = Dd * HW;          // 6,881,280
constexpr int W4 = Ww / 4;           // 56
constexpr int N4 = N / 4;            // 1,720,320

typedef float f32x4 __attribute__((ext_vector_type(4)));

__device__ __forceinline__ float sample1(const float* __restrict__ src,
                                         float cd, float ch, float cw) {
    float d0f = floorf(cd), h0f = floorf(ch), w0f = floorf(cw);
    float fd = cd - d0f, fh = ch - h0f, fw = cw - w0f;

    int d0 = (int)d0f, h0 = (int)h0f, w0 = (int)w0f;
    int d1 = d0 + 1, h1 = h0 + 1, w1 = w0 + 1;

    // Per-axis weights, zeroed when that coordinate is out of bounds.
    // Product of the three == reference's (wd*wh*ww*inb).
    float wd0 = ((unsigned)d0 < (unsigned)Dd) ? (1.0f - fd) : 0.0f;
    float wd1 = ((unsigned)d1 < (unsigned)Dd) ? fd          : 0.0f;
    float wh0 = ((unsigned)h0 < (unsigned)Hh) ? (1.0f - fh) : 0.0f;
    float wh1 = ((unsigned)h1 < (unsigned)Hh) ? fh          : 0.0f;
    float ww0 = ((unsigned)w0 < (unsigned)Ww) ? (1.0f - fw) : 0.0f;
    float ww1 = ((unsigned)w1 < (unsigned)Ww) ? fw          : 0.0f;

    // Clamped indices -> all 8 loads unconditional (v_med3 clamp, no branches).
    int d0c = min(max(d0, 0), Dd - 1), d1c = min(max(d1, 0), Dd - 1);
    int h0c = min(max(h0, 0), Hh - 1), h1c = min(max(h1, 0), Hh - 1);
    int w0c = min(max(w0, 0), Ww - 1), w1c = min(max(w1, 0), Ww - 1);

    int b00 = (d0c * Hh + h0c) * Ww;
    int b01 = (d0c * Hh + h1c) * Ww;
    int b10 = (d1c * Hh + h0c) * Ww;
    int b11 = (d1c * Hh + h1c) * Ww;

    float v000 = src[b00 + w0c], v001 = src[b00 + w1c];
    float v010 = src[b01 + w0c], v011 = src[b01 + w1c];
    float v100 = src[b10 + w0c], v101 = src[b10 + w1c];
    float v110 = src[b11 + w0c], v111 = src[b11 + w1c];

    return wd0 * (wh0 * (ww0 * v000 + ww1 * v001) +
                  wh1 * (ww0 * v010 + ww1 * v011)) +
           wd1 * (wh0 * (ww0 * v100 + ww1 * v101) +
                  wh1 * (ww0 * v110 + ww1 * v111));
}

__global__ __launch_bounds__(256)
void st3d_kernel(const float* __restrict__ src,
                 const float* __restrict__ flow,
                 float* __restrict__ out) {
    int i4 = blockIdx.x * 256 + threadIdx.x;
    if (i4 >= N4) return;

    int wq = i4 % W4;
    int t  = i4 / W4;
    int h  = t % Hh;
    int d  = t / Hh;
    float wb = (float)(wq * 4);
    float df = (float)d, hf = (float)h;

    const f32x4 fd4 = __builtin_nontemporal_load((const f32x4*)flow + i4);
    const f32x4 fh4 = __builtin_nontemporal_load((const f32x4*)(flow + N) + i4);
    const f32x4 fw4 = __builtin_nontemporal_load((const f32x4*)(flow + 2 * N) + i4);

    f32x4 res;
    res.x = sample1(src, df + fd4.x, hf + fh4.x, wb + 0.0f + fw4.x);
    res.y = sample1(src, df + fd4.y, hf + fh4.y, wb + 1.0f + fw4.y);
    res.z = sample1(src, df + fd4.z, hf + fh4.z, wb + 2.0f + fw4.z);
    res.w = sample1(src, df + fd4.w, hf + fh4.w, wb + 3.0f + fw4.w);

    __builtin_nontemporal_store(res, (f32x4*)out + i4);
}

extern "C" void kernel_launch(void* const* d_in, const int* in_sizes, int n_in,
                              void* d_out, int out_size, void* d_ws, size_t ws_size,
                              hipStream_t stream) {
    const float* src  = (const float*)d_in[0];
    const float* flow = (const float*)d_in[1];
    float* out = (float*)d_out;

    int blocks = (N4 + 255) / 256;  // 6720
    st3d_kernel<<<blocks, 256, 0, stream>>>(src, flow, out);
}

// Round 4
// 57.719 us; speedup vs baseline: 1.8978x; 1.8978x over previous
//
#include <hip/hip_runtime.h>

// 3D spatial transformer (trilinear grid sample, zeros padding).
// src:  (1,1,160,192,224) f32
// flow: (1,3,160,192,224) f32   channel 0->d, 1->h, 2->w displacement
// out:  (1,1,160,192,224) f32
//
// R3: 4 voxels/thread, NO nontemporal (it cost an extra src HBM pass),
// paired-w 8B gathers (4 gathers/voxel instead of 8, weight-swap at edges),
// XCD-aware block swizzle (each XCD owns a contiguous 20-d-slice slab of
// src = 3.4MB, fits the 4MB per-XCD L2).

constexpr int Dd = 160;
constexpr int Hh = 192;
constexpr int Ww = 224;
constexpr int HW = Hh * Ww;          // 43008
constexpr int N  = Dd * HW;          // 6,881,280
constexpr int W4 = Ww / 4;           // 56
constexpr int N4 = N / 4;            // 1,720,320
constexpr int NBLK = N4 / 256;       // 6720, divisible by 8

typedef float f32x4 __attribute__((ext_vector_type(4)));
typedef float f32x2 __attribute__((ext_vector_type(2)));

__device__ __forceinline__ f32x2 load2(const float* __restrict__ p) {
    f32x2 v;
    __builtin_memcpy(&v, p, sizeof(v));  // align-4 8B load -> global_load_dwordx2
    return v;
}

__device__ __forceinline__ float sample1(const float* __restrict__ src,
                                         float cd, float ch, float cw) {
    float d0f = floorf(cd), h0f = floorf(ch), w0f = floorf(cw);
    float fd = cd - d0f, fh = ch - h0f, fw = cw - w0f;

    int d0 = (int)d0f, h0 = (int)h0f, w0 = (int)w0f;

    // Per-axis weights, zeroed when that coordinate is out of bounds.
    // Product of the three == reference's (wd*wh*ww*inb).
    float wd0 = ((unsigned)d0       < (unsigned)Dd) ? (1.0f - fd) : 0.0f;
    float wd1 = ((unsigned)(d0 + 1) < (unsigned)Dd) ? fd          : 0.0f;
    float wh0 = ((unsigned)h0       < (unsigned)Hh) ? (1.0f - fh) : 0.0f;
    float wh1 = ((unsigned)(h0 + 1) < (unsigned)Hh) ? fh          : 0.0f;
    float ww0 = ((unsigned)w0       < (unsigned)Ww) ? (1.0f - fw) : 0.0f;
    float ww1 = ((unsigned)(w0 + 1) < (unsigned)Ww) ? fw          : 0.0f;

    // Paired-w gather: one 8B load covers {wb, wb+1}. Base clamped so the
    // pair is always in-bounds. If w0 is outside [0, Ww-2], the needed value
    // sits on the other element of the pair and the OOB weight is already 0,
    // so swapping (wx,wy) is exact:
    //   w0=-1  -> pair=[0,1],        need ww1*src[0] -> wx=ww1 on pair.x
    //   w0=Ww-1-> pair=[Ww-2,Ww-1],  need ww0*src[Ww-1] -> wy=ww0 on pair.y
    //   w0<=-2 or w0>=Ww -> both weights 0, don't care.
    int wb = min(max(w0, 0), Ww - 2);
    bool in = (w0 == wb);
    float wx = in ? ww0 : ww1;
    float wy = in ? ww1 : ww0;

    int d0c = min(max(d0, 0), Dd - 1), d1c = min(max(d0 + 1, 0), Dd - 1);
    int h0c = min(max(h0, 0), Hh - 1), h1c = min(max(h0 + 1, 0), Hh - 1);

    const float* r00 = src + (d0c * Hh + h0c) * Ww + wb;
    const float* r01 = src + (d0c * Hh + h1c) * Ww + wb;
    const float* r10 = src + (d1c * Hh + h0c) * Ww + wb;
    const float* r11 = src + (d1c * Hh + h1c) * Ww + wb;

    f32x2 p00 = load2(r00), p01 = load2(r01);
    f32x2 p10 = load2(r10), p11 = load2(r11);

    float v00 = wx * p00.x + wy * p00.y;
    float v01 = wx * p01.x + wy * p01.y;
    float v10 = wx * p10.x + wy * p10.y;
    float v11 = wx * p11.x + wy * p11.y;

    return wd0 * (wh0 * v00 + wh1 * v01) + wd1 * (wh0 * v10 + wh1 * v11);
}

__global__ __launch_bounds__(256)
void st3d_kernel(const float* __restrict__ src,
                 const float* __restrict__ flow,
                 float* __restrict__ out) {
    // XCD-aware swizzle: 6720 blocks % 8 XCDs == 0 -> bijective chunked map.
    // Each XCD gets 840 consecutive blocks = contiguous ~20 d-slices of src
    // (3.4MB slab, fits 4MB per-XCD L2).
    int bid = blockIdx.x;
    int swz = (bid & 7) * (NBLK / 8) + (bid >> 3);

    int i4 = swz * 256 + threadIdx.x;

    int wq = i4 % W4;
    int t  = i4 / W4;
    int h  = t % Hh;
    int d  = t / Hh;
    float wbf = (float)(wq * 4);
    float df = (float)d, hf = (float)h;

    const f32x4 fd4 = *((const f32x4*)flow + i4);
    const f32x4 fh4 = *((const f32x4*)(flow + N) + i4);
    const f32x4 fw4 = *((const f32x4*)(flow + 2 * N) + i4);

    f32x4 res;
    res.x = sample1(src, df + fd4.x, hf + fh4.x, wbf + 0.0f + fw4.x);
    res.y = sample1(src, df + fd4.y, hf + fh4.y, wbf + 1.0f + fw4.y);
    res.z = sample1(src, df + fd4.z, hf + fh4.z, wbf + 2.0f + fw4.z);
    res.w = sample1(src, df + fd4.w, hf + fh4.w, wbf + 3.0f + fw4.w);

    *((f32x4*)out + i4) = res;
}

extern "C" void kernel_launch(void* const* d_in, const int* in_sizes, int n_in,
                              void* d_out, int out_size, void* d_ws, size_t ws_size,
                              hipStream_t stream) {
    const float* src  = (const float*)d_in[0];
    const float* flow = (const float*)d_in[1];
    float* out = (float*)d_out;

    st3d_kernel<<<NBLK, 256, 0, stream>>>(src, flow, out);
}

// Round 5
// 56.871 us; speedup vs baseline: 1.9261x; 1.0149x over previous
//
#include <hip/hip_runtime.h>

// 3D spatial transformer (trilinear grid sample, zeros padding).
// src:  (1,1,160,192,224) f32
// flow: (1,3,160,192,224) f32   channel 0->d, 1->h, 2->w displacement
// out:  (1,1,160,192,224) f32
//
// R5: VMEM-issue-bound (R4 measured 0.97 VMEM instr/CU/cycle). Reduce the
// instruction count structurally: prep kernel packs the 2x2x2 corner patch
// of every voxel into 8 bytes (4 x bf16 pairs), so the main kernel does ONE
// 16B gather per voxel (covers w0,w0+1) instead of four 8B gathers.
// Per-axis weight-swap trick handles all clamp/OOB edges exactly (OOB axis
// weight is zeroed, so the swapped slot's value is never actually used).

constexpr int Dd = 160;
constexpr int Hh = 192;
constexpr int Ww = 224;
constexpr int HW = Hh * Ww;          // 43008
constexpr int N  = Dd * HW;          // 6,881,280
constexpr int W4 = Ww / 4;           // 56
constexpr int N4 = N / 4;            // 1,720,320
constexpr int NBLK = N4 / 256;       // 6720, divisible by 8

typedef float    f32x4 __attribute__((ext_vector_type(4)));
typedef float    f32x2 __attribute__((ext_vector_type(2)));
typedef unsigned u32x4 __attribute__((ext_vector_type(4)));

__device__ __forceinline__ unsigned bf16rne(float x) {
    unsigned u = __builtin_bit_cast(unsigned, x);
    return (u + 0x7fffu + ((u >> 16) & 1u)) >> 16;  // round-nearest-even
}

__device__ __forceinline__ float bflo(unsigned u) {  // low bf16 -> f32
    return __builtin_bit_cast(float, u << 16);
}
__device__ __forceinline__ float bfhi(unsigned u) {  // high bf16 -> f32
    return __builtin_bit_cast(float, u & 0xffff0000u);
}

// ---------------- prep: pack 2x2x2 corner patches ----------------
// P[i] (i = (d*Hh+h)*Ww+w), 8 bytes:
//   word0 = bf16(src[d][h][w])    | bf16(src[d][h+1c][w])  <<16
//   word1 = bf16(src[d+1c][h][w]) | bf16(src[d+1c][h+1c][w])<<16
// (h+1c / d+1c clamped to volume)
__global__ __launch_bounds__(256)
void pack_kernel(const float* __restrict__ src, unsigned* __restrict__ P32) {
    int i4 = blockIdx.x * 256 + threadIdx.x;    // group of 4 consecutive w
    int wq = i4 % W4;
    int t  = i4 / W4;
    int h  = t % Hh;
    int d  = t / Hh;
    int hc = min(h + 1, Hh - 1);
    int dc = min(d + 1, Dd - 1);
    int wo = wq * 4;

    f32x4 a, b, c, e;
    __builtin_memcpy(&a, src + (d  * Hh + h ) * Ww + wo, 16);
    __builtin_memcpy(&b, src + (d  * Hh + hc) * Ww + wo, 16);
    __builtin_memcpy(&c, src + (dc * Hh + h ) * Ww + wo, 16);
    __builtin_memcpy(&e, src + (dc * Hh + hc) * Ww + wo, 16);

    u32x4 q0, q1;
    q0.x = bf16rne(a.x) | (bf16rne(b.x) << 16);
    q0.y = bf16rne(c.x) | (bf16rne(e.x) << 16);
    q0.z = bf16rne(a.y) | (bf16rne(b.y) << 16);
    q0.w = bf16rne(c.y) | (bf16rne(e.y) << 16);
    q1.x = bf16rne(a.z) | (bf16rne(b.z) << 16);
    q1.y = bf16rne(c.z) | (bf16rne(e.z) << 16);
    q1.z = bf16rne(a.w) | (bf16rne(b.w) << 16);
    q1.w = bf16rne(c.w) | (bf16rne(e.w) << 16);

    *((u32x4*)(P32 + (size_t)i4 * 8))     = q0;
    *((u32x4*)(P32 + (size_t)i4 * 8 + 4)) = q1;
}

// ---------------- main: one 16B gather per voxel ----------------
__device__ __forceinline__ float sample_packed(const unsigned* __restrict__ P32,
                                               float cd, float ch, float cw) {
    float d0f = floorf(cd), h0f = floorf(ch), w0f = floorf(cw);
    float fd = cd - d0f, fh = ch - h0f, fw = cw - w0f;
    int d0 = (int)d0f, h0 = (int)h0f, w0 = (int)w0f;

    // Per-axis weights, zeroed when that coordinate is out of bounds
    // (product == reference's wd*wh*ww*inb).
    float wd0 = ((unsigned)d0       < (unsigned)Dd) ? (1.0f - fd) : 0.0f;
    float wd1 = ((unsigned)(d0 + 1) < (unsigned)Dd) ? fd          : 0.0f;
    float wh0 = ((unsigned)h0       < (unsigned)Hh) ? (1.0f - fh) : 0.0f;
    float wh1 = ((unsigned)(h0 + 1) < (unsigned)Hh) ? fh          : 0.0f;
    float ww0 = ((unsigned)w0       < (unsigned)Ww) ? (1.0f - fw) : 0.0f;
    float ww1 = ((unsigned)(w0 + 1) < (unsigned)Ww) ? fw          : 0.0f;

    // Clamped bases; swap the weight pair when the base clamped up from
    // below (the needed value then sits in the other slot, and the OOB
    // slot's weight is already 0). For w, clamping to Ww-2 at the top edge
    // also swaps (w0=223 -> pair=[222,223], need ww0 on .y).
    int db = min(max(d0, 0), Dd - 1);
    int hb = min(max(h0, 0), Hh - 1);
    int wb = min(max(w0, 0), Ww - 2);
    bool sd = d0 < 0;
    bool sh = h0 < 0;
    bool sw = w0 != wb;

    float wdx = sd ? wd1 : wd0, wdy = sd ? wd0 : wd1;
    float whx = sh ? wh1 : wh0, why = sh ? wh0 : wh1;
    float wwx = sw ? ww1 : ww0, wwy = sw ? ww0 : ww1;

    u32x4 q;
    __builtin_memcpy(&q, P32 + (size_t)((db * Hh + hb) * Ww + wb) * 2, 16);

    // q.x: (d,h | d,h+1) @ wb       q.y: (d+1,h | d+1,h+1) @ wb
    // q.z: (d,h | d,h+1) @ wb+1     q.w: (d+1,h | d+1,h+1) @ wb+1
    float s0 = wdx * (whx * bflo(q.x) + why * bfhi(q.x)) +
               wdy * (whx * bflo(q.y) + why * bfhi(q.y));
    float s1 = wdx * (whx * bflo(q.z) + why * bfhi(q.z)) +
               wdy * (whx * bflo(q.w) + why * bfhi(q.w));
    return wwx * s0 + wwy * s1;
}

__global__ __launch_bounds__(256)
void st3d_packed_kernel(const unsigned* __restrict__ P32,
                        const float* __restrict__ flow,
                        float* __restrict__ out) {
    // XCD-aware swizzle: each XCD gets 840 consecutive blocks = a contiguous
    // ~20-d-slice slab (P slab ~6.9MB -> L2+L3 resident).
    int bid = blockIdx.x;
    int swz = (bid & 7) * (NBLK / 8) + (bid >> 3);
    int i4 = swz * 256 + threadIdx.x;

    int wq = i4 % W4;
    int t  = i4 / W4;
    int h  = t % Hh;
    int d  = t / Hh;
    float wbf = (float)(wq * 4);
    float df = (float)d, hf = (float)h;

    f32x4 fd4, fh4, fw4;
    __builtin_memcpy(&fd4, (const f32x4*)flow + i4, 16);
    __builtin_memcpy(&fh4, (const f32x4*)(flow + N) + i4, 16);
    __builtin_memcpy(&fw4, (const f32x4*)(flow + 2 * N) + i4, 16);

    f32x4 res;
    res.x = sample_packed(P32, df + fd4.x, hf + fh4.x, wbf + 0.0f + fw4.x);
    res.y = sample_packed(P32, df + fd4.y, hf + fh4.y, wbf + 1.0f + fw4.y);
    res.z = sample_packed(P32, df + fd4.z, hf + fh4.z, wbf + 2.0f + fw4.z);
    res.w = sample_packed(P32, df + fd4.w, hf + fh4.w, wbf + 3.0f + fw4.w);

    *((f32x4*)out + i4) = res;
}

// ---------------- fallback (R4 kernel) if ws too small ----------------
__device__ __forceinline__ float sample1(const float* __restrict__ src,
                                         float cd, float ch, float cw) {
    float d0f = floorf(cd), h0f = floorf(ch), w0f = floorf(cw);
    float fd = cd - d0f, fh = ch - h0f, fw = cw - w0f;
    int d0 = (int)d0f, h0 = (int)h0f, w0 = (int)w0f;

    float wd0 = ((unsigned)d0       < (unsigned)Dd) ? (1.0f - fd) : 0.0f;
    float wd1 = ((unsigned)(d0 + 1) < (unsigned)Dd) ? fd          : 0.0f;
    float wh0 = ((unsigned)h0       < (unsigned)Hh) ? (1.0f - fh) : 0.0f;
    float wh1 = ((unsigned)(h0 + 1) < (unsigned)Hh) ? fh          : 0.0f;
    float ww0 = ((unsigned)w0       < (unsigned)Ww) ? (1.0f - fw) : 0.0f;
    float ww1 = ((unsigned)(w0 + 1) < (unsigned)Ww) ? fw          : 0.0f;

    int wb = min(max(w0, 0), Ww - 2);
    bool in = (w0 == wb);
    float wx = in ? ww0 : ww1;
    float wy = in ? ww1 : ww0;

    int d0c = min(max(d0, 0), Dd - 1), d1c = min(max(d0 + 1, 0), Dd - 1);
    int h0c = min(max(h0, 0), Hh - 1), h1c = min(max(h0 + 1, 0), Hh - 1);

    f32x2 p00, p01, p10, p11;
    __builtin_memcpy(&p00, src + (d0c * Hh + h0c) * Ww + wb, 8);
    __builtin_memcpy(&p01, src + (d0c * Hh + h1c) * Ww + wb, 8);
    __builtin_memcpy(&p10, src + (d1c * Hh + h0c) * Ww + wb, 8);
    __builtin_memcpy(&p11, src + (d1c * Hh + h1c) * Ww + wb, 8);

    float v00 = wx * p00.x + wy * p00.y;
    float v01 = wx * p01.x + wy * p01.y;
    float v10 = wx * p10.x + wy * p10.y;
    float v11 = wx * p11.x + wy * p11.y;
    return wd0 * (wh0 * v00 + wh1 * v01) + wd1 * (wh0 * v10 + wh1 * v11);
}

__global__ __launch_bounds__(256)
void st3d_kernel(const float* __restrict__ src,
                 const float* __restrict__ flow,
                 float* __restrict__ out) {
    int bid = blockIdx.x;
    int swz = (bid & 7) * (NBLK / 8) + (bid >> 3);
    int i4 = swz * 256 + threadIdx.x;

    int wq = i4 % W4;
    int t  = i4 / W4;
    int h  = t % Hh;
    int d  = t / Hh;
    float wbf = (float)(wq * 4);
    float df = (float)d, hf = (float)h;

    f32x4 fd4, fh4, fw4;
    __builtin_memcpy(&fd4, (const f32x4*)flow + i4, 16);
    __builtin_memcpy(&fh4, (const f32x4*)(flow + N) + i4, 16);
    __builtin_memcpy(&fw4, (const f32x4*)(flow + 2 * N) + i4, 16);

    f32x4 res;
    res.x = sample1(src, df + fd4.x, hf + fh4.x, wbf + 0.0f + fw4.x);
    res.y = sample1(src, df + fd4.y, hf + fh4.y, wbf + 1.0f + fw4.y);
    res.z = sample1(src, df + fd4.z, hf + fh4.z, wbf + 2.0f + fw4.z);
    res.w = sample1(src, df + fd4.w, hf + fh4.w, wbf + 3.0f + fw4.w);

    *((f32x4*)out + i4) = res;
}

extern "C" void kernel_launch(void* const* d_in, const int* in_sizes, int n_in,
                              void* d_out, int out_size, void* d_ws, size_t ws_size,
                              hipStream_t stream) {
    const float* src  = (const float*)d_in[0];
    const float* flow = (const float*)d_in[1];
    float* out = (float*)d_out;

    if (ws_size >= (size_t)N * 8) {
        unsigned* P32 = (unsigned*)d_ws;
        pack_kernel<<<NBLK, 256, 0, stream>>>(src, P32);
        st3d_packed_kernel<<<NBLK, 256, 0, stream>>>(P32, flow, out);
    } else {
        st3d_kernel<<<NBLK, 256, 0, stream>>>(src, flow, out);
    }
}